// Round 4
// baseline (3343.576 us; speedup 1.0000x reference)
//
#include <hip/hip_runtime.h>
#include <stdint.h>

// ---------------------------------------------------------------------------
// NonLinearCoSeqAttn: B=16, LX=LY=2048, D=H=1024
//   px = relu(x @ Wx^T)  [f16 ws]
//   py = relu(y @ Wy^T)  [f16 ws]
//   s  = mask(px @ py^T) [f32 ws, adaptive batch chunking]
//   row/col softmax stats (m, 1/l)
//   y_h = softmax_row(s) @ y   -> d_out[0 : B*L*D]       (FLOAT32)
//   x_h = softmax_col(s)^T @ x -> d_out[B*L*D : 2*B*L*D] (FLOAT32)
// Runtime detection (device-side, no host sync): mask width (int32 vs u8),
// input dtype (packed bf16 vs f32). Output stored as f32 — the reference's
// declared output dtype (H1: explains the bit-identical 4.718 failures).
// Batch indexing: A/C use chunk-local blockIdx.z; input-tensor B and masks
// use global batch gb0+z so host never needs the element width.
// ---------------------------------------------------------------------------

#define BM 128
#define BN 128
#define BK 64
#define LDSK 72   // BK + 8 pad: 16B-aligned, breaks pow2 stride

typedef short    short8  __attribute__((ext_vector_type(8)));
typedef _Float16 half8   __attribute__((ext_vector_type(8)));
typedef float    floatx4 __attribute__((ext_vector_type(4)));

static __device__ __forceinline__ float b2f(unsigned short s) {
    union { unsigned int u; float f; } v; v.u = ((unsigned int)s) << 16; return v.f;
}
static __device__ __forceinline__ _Float16 f2h(float f) { return (_Float16)f; }

// flags[0]: 1 => masks are 1-byte bools, 0 => int32
// flags[1]: 1 => tensor inputs are f32,   0 => packed bf16
__global__ void detect_kernel(const unsigned int* __restrict__ xm,
                              const unsigned int* __restrict__ xv,
                              int* __restrict__ flags)
{
    __shared__ int anyBig, cnt;
    if (threadIdx.x == 0) { anyBig = 0; cnt = 0; }
    __syncthreads();
    int big = 0;
    for (int i = threadIdx.x; i < 2048; i += 256)
        if (xm[i] > 1u) big = 1;
    if (big) atomicOr(&anyBig, 1);
    int c = 0;
    for (int i = threadIdx.x; i < 4096; i += 256) {
        const unsigned lo = xv[i] & 0xFFFFu;      // low ushort of each word
        const unsigned e  = (lo >> 7) & 0xFFu;    // its bf16 exponent if packed
        if ((lo & 0x7FFFu) == 0u || (e >= 96u && e <= 143u)) c++;
    }
    atomicAdd(&cnt, c);
    __syncthreads();
    if (threadIdx.x == 0) {
        flags[0] = anyBig;
        flags[1] = (cnt < 3600) ? 1 : 0;  // bf16 => ~4096 in-band; f32 => ~650
    }
}

// EPI: 0 = relu -> f16 ws | 1 = mask -> f32 ws | 2 = *linv -> f32 d_out
// ASRC: 0 = input tensor (bf16|f32), 1 = f16 ws, 2 = f32 s with exp()
// BSRC: 0 = input tensor (bf16|f32), 1 = f16 ws
// ATRANS: A[m][k] = Aglob[k][m] (ASRC==2 only; s^T path)
// BTRANS: B given [K][N] row-major; staged transposed
// B batch offset uses (gb0 + blockIdx.z) * saB elements of the DETECTED width.
template<int EPI, bool ATRANS, bool BTRANS, int ASRC, int BSRC>
__global__ __launch_bounds__(256, 2)
void gemm_kernel(const void* __restrict__ Agv, const void* __restrict__ Bgv,
                 void* __restrict__ Cgv,
                 const float* __restrict__ mstat, const float* __restrict__ linv,
                 const int* __restrict__ xmask, const int* __restrict__ ymask,
                 const int* __restrict__ gflags, int gb0,
                 int K, int lda, int ldb, int ldc,
                 long long saA, long long saB, long long saC, int saStat)
{
    const int b = blockIdx.z;
    const int inf32 = (ASRC == 0 || BSRC == 0 || EPI == 1) ? gflags[1] : 0;

    const unsigned short* Ag16 = (const unsigned short*)Agv + (long long)b * saA;
    const float*          Agf  = (const float*)Agv + (long long)b * saA;
    const long long boff = (BSRC == 0) ? (long long)(gb0 + b) * saB
                                       : (long long)b * saB;
    const unsigned short* Bg16 = (const unsigned short*)Bgv + boff;
    const float*          Bgf  = (const float*)Bgv + boff;
    if (ASRC == 2) mstat += (long long)b * saStat;
    if (EPI == 2)  linv  += (long long)b * saStat;

    __shared__ _Float16 As[BM * LDSK];
    __shared__ _Float16 Bs[BN * LDSK];

    const int t    = threadIdx.x;
    const int lane = t & 63;
    const int wave = t >> 6;
    const int wm   = (wave >> 1) << 6;   // 2x2 wave grid, 64x64 per wave
    const int wn   = (wave & 1) << 6;
    const int l16  = lane & 15;
    const int quad = lane >> 4;
    const int m0   = blockIdx.y * BM;
    const int n0   = blockIdx.x * BN;

    floatx4 acc[4][4];
    #pragma unroll
    for (int i = 0; i < 4; i++)
        #pragma unroll
        for (int j = 0; j < 4; j++)
            acc[i][j] = (floatx4){0.f, 0.f, 0.f, 0.f};

    for (int k0 = 0; k0 < K; k0 += BK) {
        // ---- stage A -> As[m][k] (f16) ----
        if (!ATRANS) {
            #pragma unroll
            for (int c = t; c < BM * (BK / 8); c += 256) {
                const int row = c >> 3;
                const int kc  = (c & 7) << 3;
                half8 o;
                if (ASRC == 2) {
                    const float* src = Agf + (long long)(m0 + row) * lda + k0 + kc;
                    const float  mr  = mstat[m0 + row];
                    #pragma unroll
                    for (int j = 0; j < 8; j++) o[j] = f2h(__expf(src[j] - mr));
                } else if (ASRC == 1) {
                    o = *(const half8*)(Ag16 + (long long)(m0 + row) * lda + k0 + kc);
                } else if (inf32) {
                    const float* src = Agf + (long long)(m0 + row) * lda + k0 + kc;
                    #pragma unroll
                    for (int j = 0; j < 8; j++) o[j] = f2h(src[j]);
                } else {
                    short8 r = *(const short8*)(Ag16 + (long long)(m0 + row) * lda + k0 + kc);
                    #pragma unroll
                    for (int j = 0; j < 8; j++) o[j] = f2h(b2f((unsigned short)r[j]));
                }
                *(half8*)&As[row * LDSK + kc] = o;
            }
        } else {  // ASRC==2: transpose s tile (rows=k, cols=m)
            #pragma unroll
            for (int c = t; c < BK * (BM / 8); c += 256) {
                const int gr = c >> 4;
                const int mc = (c & 15) << 3;
                const float* src = Agf + (long long)(k0 + gr) * lda + m0 + mc;
                #pragma unroll
                for (int j = 0; j < 8; j++)
                    As[(mc + j) * LDSK + gr] = f2h(__expf(src[j] - mstat[m0 + mc + j]));
            }
        }
        // ---- stage B -> Bs[n][k] (f16) ----
        if (!BTRANS) {
            #pragma unroll
            for (int c = t; c < BN * (BK / 8); c += 256) {
                const int row = c >> 3;
                const int kc  = (c & 7) << 3;
                half8 o;
                if (BSRC == 1) {
                    o = *(const half8*)(Bg16 + (long long)(n0 + row) * ldb + k0 + kc);
                } else if (inf32) {
                    const float* src = Bgf + (long long)(n0 + row) * ldb + k0 + kc;
                    #pragma unroll
                    for (int j = 0; j < 8; j++) o[j] = f2h(src[j]);
                } else {
                    short8 r = *(const short8*)(Bg16 + (long long)(n0 + row) * ldb + k0 + kc);
                    #pragma unroll
                    for (int j = 0; j < 8; j++) o[j] = f2h(b2f((unsigned short)r[j]));
                }
                *(half8*)&Bs[row * LDSK + kc] = o;
            }
        } else {  // BSRC==0: B is [K][N] row-major input; transpose into LDS
            #pragma unroll
            for (int c = t; c < BK * (BN / 8); c += 256) {
                const int gr = c >> 4;
                const int nc = (c & 15) << 3;
                if (inf32) {
                    const float* src = Bgf + (long long)(k0 + gr) * ldb + n0 + nc;
                    #pragma unroll
                    for (int j = 0; j < 8; j++) Bs[(nc + j) * LDSK + gr] = f2h(src[j]);
                } else {
                    const unsigned short* src = Bg16 + (long long)(k0 + gr) * ldb + n0 + nc;
                    #pragma unroll
                    for (int j = 0; j < 8; j++) Bs[(nc + j) * LDSK + gr] = f2h(b2f(src[j]));
                }
            }
        }
        __syncthreads();
        // ---- MFMA f16: A[m=lane&15][k=quad*8+j], B[n=lane&15][k=quad*8+j] ----
        #pragma unroll
        for (int kk = 0; kk < BK; kk += 32) {
            half8 af[4], bfr[4];
            #pragma unroll
            for (int i = 0; i < 4; i++)
                af[i] = *(const half8*)&As[(wm + i * 16 + l16) * LDSK + kk + quad * 8];
            #pragma unroll
            for (int i = 0; i < 4; i++)
                bfr[i] = *(const half8*)&Bs[(wn + i * 16 + l16) * LDSK + kk + quad * 8];
            #pragma unroll
            for (int i = 0; i < 4; i++)
                #pragma unroll
                for (int j = 0; j < 4; j++)
                    acc[i][j] = __builtin_amdgcn_mfma_f32_16x16x32_f16(af[i], bfr[j], acc[i][j], 0, 0, 0);
        }
        __syncthreads();
    }

    int u8mode = 0;
    if (EPI == 1) u8mode = gflags[0];
    const unsigned char* xm8 = (const unsigned char*)xmask;
    const unsigned char* ym8 = (const unsigned char*)ymask;

    // ---- epilogue: C/D layout col=lane&15, row=quad*4+reg (m89-verified) ----
    #pragma unroll
    for (int i = 0; i < 4; i++) {
        #pragma unroll
        for (int j = 0; j < 4; j++) {
            #pragma unroll
            for (int r = 0; r < 4; r++) {
                const int grow = m0 + wm + i * 16 + quad * 4 + r;
                const int gcol = n0 + wn + j * 16 + l16;
                const float v = acc[i][j][r];
                const long long cidx = (long long)b * saC + (long long)grow * ldc + gcol;
                if (EPI == 0) {
                    ((_Float16*)Cgv)[cidx] = f2h(fmaxf(v, 0.f));
                } else if (EPI == 1) {
                    const long long ix = (long long)(gb0 + b) * saStat + grow;
                    const long long iy = (long long)(gb0 + b) * saStat + gcol;
                    const bool mk = u8mode
                        ? ((xm8[ix] != 0) || (ym8[iy] != 0))
                        : ((xmask[ix] != 0) || (ymask[iy] != 0));
                    ((float*)Cgv)[cidx] = mk ? -1e30f : v;
                } else {
                    ((float*)Cgv)[cidx] = v * linv[grow];   // FLOAT32 output
                }
            }
        }
    }
}

// one wave per row, 4 rows per block
__global__ __launch_bounds__(256)
void rowstats_kernel(const float* __restrict__ s, float* __restrict__ mrow,
                     float* __restrict__ linv, int ncols)
{
    const int r    = blockIdx.x * 4 + (threadIdx.x >> 6);
    const int lane = threadIdx.x & 63;
    const float* row = s + (long long)r * ncols;
    float m = -INFINITY, l = 0.f;
    for (int j = lane; j < ncols; j += 64) {
        const float v = row[j];
        if (v > m) { l = l * __expf(m - v) + 1.f; m = v; }
        else       { l += __expf(v - m); }
    }
    #pragma unroll
    for (int off = 32; off > 0; off >>= 1) {
        const float m2 = __shfl_xor(m, off);
        const float l2 = __shfl_xor(l, off);
        const float M  = fmaxf(m, m2);
        l = l * __expf(m - M) + l2 * __expf(m2 - M);
        m = M;
    }
    if (lane == 0) { mrow[r] = m; linv[r] = 1.f / l; }
}

// 64 columns of one batch per block; 4 waves split the rows; coalesced reads
__global__ __launch_bounds__(256)
void colstats_kernel(const float* __restrict__ s, float* __restrict__ mcol,
                     float* __restrict__ lcinv)
{
    __shared__ float mpart[4][64], lpart[4][64];
    const int b    = blockIdx.x >> 5;
    const int c0   = (blockIdx.x & 31) << 6;
    const int wave = threadIdx.x >> 6;
    const int lane = threadIdx.x & 63;
    const float* sb = s + (long long)b * 2048 * 2048;
    const int col = c0 + lane;
    float m = -INFINITY, l = 0.f;
    const int i0 = wave * 512;
    for (int i = i0; i < i0 + 512; i++) {
        const float v = sb[(long long)i * 2048 + col];
        if (v > m) { l = l * __expf(m - v) + 1.f; m = v; }
        else       { l += __expf(v - m); }
    }
    mpart[wave][lane] = m; lpart[wave][lane] = l;
    __syncthreads();
    if (wave == 0) {
        float M = m, Lr = l;
        #pragma unroll
        for (int w = 1; w < 4; w++) {
            const float m2 = mpart[w][lane], l2 = lpart[w][lane];
            const float Mn = fmaxf(M, m2);
            Lr = Lr * __expf(M - Mn) + l2 * __expf(m2 - Mn);
            M = Mn;
        }
        mcol[b * 2048 + col]  = M;
        lcinv[b * 2048 + col] = 1.f / Lr;
    }
}

extern "C" void kernel_launch(void* const* d_in, const int* in_sizes, int n_in,
                              void* d_out, int out_size, void* d_ws, size_t ws_size,
                              hipStream_t stream)
{
    const int B = 16, L = 2048, D = 1024, H = 1024;
    const void* x  = d_in[0];                 // [B,L,D] bf16 or f32 (detected)
    const void* y  = d_in[1];                 // [B,L,D]
    const int* xmask = (const int*)d_in[2];   // [B,L] int32 or u8 (detected)
    const int* ymask = (const int*)d_in[3];
    const void* Wx = d_in[4];                 // [H,D]
    const void* Wy = d_in[5];

    // ws: px f16 | py f16 | mrow|lrinv|mcol|lcinv | flags | s (adaptive chunk)
    unsigned short* px = (unsigned short*)d_ws;
    unsigned short* py = px + (size_t)B * L * H;
    float* mrow  = (float*)(py + (size_t)B * L * H);
    float* lrinv = mrow  + (size_t)B * L;
    float* mcol  = lrinv + (size_t)B * L;
    float* lcinv = mcol  + (size_t)B * L;
    int*   flags = (int*)(lcinv + (size_t)B * L);
    float* s     = (float*)(flags + 16);

    const long long fixed_bytes =
        (long long)2 * B * L * H * 2 + (long long)4 * B * L * 4 + 64;
    const long long per_batch_s = (long long)L * L * 4;
    long long avail = (long long)ws_size - fixed_bytes;
    int nc = (int)(avail / per_batch_s);
    if (nc < 1) nc = 1;
    if (nc > B) nc = B;

    float* yh = (float*)d_out;                 // FLOAT32 outputs (H1)
    float* xh = yh + (size_t)B * L * D;

    dim3 blk(256);

    detect_kernel<<<1, 256, 0, stream>>>((const unsigned int*)xmask,
                                         (const unsigned int*)x, flags);

    // projections: px = relu(x @ Wx^T), py = relu(y @ Wy^T)  (NT, f16 MFMA)
    gemm_kernel<0, false, false, 0, 0><<<dim3(H / BN, (B * L) / BM, 1), blk, 0, stream>>>(
        x, Wx, px, nullptr, nullptr, nullptr, nullptr, flags, 0,
        D, D, D, H, 0, 0, 0, 0);
    gemm_kernel<0, false, false, 0, 0><<<dim3(H / BN, (B * L) / BM, 1), blk, 0, stream>>>(
        y, Wy, py, nullptr, nullptr, nullptr, nullptr, flags, 0,
        D, D, D, H, 0, 0, 0, 0);

    for (int b0 = 0; b0 < B; b0 += nc) {
        const int cur = (B - b0 < nc) ? (B - b0) : nc;
        // s = mask(px @ py^T)  (NT, f16 ws in, f32 out)
        gemm_kernel<1, false, false, 1, 1><<<dim3(L / BN, L / BM, cur), blk, 0, stream>>>(
            px + (size_t)b0 * L * H, py + (size_t)b0 * L * H, s,
            nullptr, nullptr, xmask, ymask, flags, b0,
            H, H, H, L, (long long)L * H, (long long)L * H, (long long)L * L, L);
        rowstats_kernel<<<dim3(cur * L / 4), blk, 0, stream>>>(s, mrow, lrinv, L);
        colstats_kernel<<<dim3(cur * (L / 64)), blk, 0, stream>>>(s, mcol, lcinv);
        // y_h = softmax_row(s) @ y   (B batch offset = (b0+z)*L*D in-kernel)
        gemm_kernel<2, false, true, 2, 0><<<dim3(D / BN, L / BM, cur), blk, 0, stream>>>(
            s, y, yh + (size_t)b0 * L * D,
            mrow, lrinv, nullptr, nullptr, flags, b0,
            L, L, D, D, (long long)L * L, (long long)L * D, (long long)L * D, L);
        // x_h = softmax_col(s)^T @ x
        gemm_kernel<2, true, true, 2, 0><<<dim3(D / BN, L / BM, cur), blk, 0, stream>>>(
            s, x, xh + (size_t)b0 * L * D,
            mcol, lcinv, nullptr, nullptr, flags, b0,
            L, L, D, D, (long long)L * L, (long long)L * D, (long long)L * D, L);
    }
    (void)in_sizes; (void)n_in; (void)out_size; (void)ws_size;
}

// Round 6
// 1964.325 us; speedup vs baseline: 1.7022x; 1.7022x over previous
//
#include <hip/hip_runtime.h>
#include <stdint.h>

// ---------------------------------------------------------------------------
// NonLinearCoSeqAttn: B=16, LX=LY=2048, D=H=1024
// Pipeline (all f16 MFMA GEMMs):
//   detect: input dtype (bf16|f32), mask width (i32|u8)
//   init:   mrow/mcol atomic-max slots (monotonic-uint), lrow/lcol = 0
//   xT,yT = transpose(x,y) -> f16 [B][D][L]          (LDS-tiled transpose)
//   px,py = relu(x@Wx^T), relu(y@Wy^T) -> f16 ws     (EPI0 GEMM, INRAW)
//   per chunk of nc batches:
//     s = mask(px@py^T) -> f32 ws; epilogue atomicMax mrow/mcol  (EPI1)
//     transform: Pr=exp(s-mrow) f16 [x][y]; Pct=exp(s-mcol)^T f16 [y][x];
//                atomicAdd lrow/lcol
//     y_h = (Pr @ yT^T)/lrow -> f32 d_out            (EPI3)
//     x_h = (Pct @ xT^T)/lcol -> f32 d_out           (EPI3)
// LDS layout lesson (R4 counters): padded 144B rows caused 5.2e8 bank-conflict
// cycles (84% of kernel) on ALL gemm dispatches incl. non-transposing EPI0.
// m97/m98 evidence: unpadded 128B rows -> 1.7e7. So BK rows are UNPADDED,
// staging is contiguous (lane l -> LDS bytes 16l..16l+15), and f16-ws GEMMs
// stage via global_load_lds width=16 (m97's 1.69x step).
// ---------------------------------------------------------------------------

#define BM 128
#define BN 128
#define BK 64   // f16: row = 128 B, unpadded (m97 layout)

typedef short    short8  __attribute__((ext_vector_type(8)));
typedef _Float16 half8   __attribute__((ext_vector_type(8)));
typedef _Float16 half4   __attribute__((ext_vector_type(4)));
typedef float    floatx4 __attribute__((ext_vector_type(4)));

static __device__ __forceinline__ float b2f(unsigned short s) {
    union { unsigned int u; float f; } v; v.u = ((unsigned int)s) << 16; return v.f;
}
static __device__ __forceinline__ _Float16 f2h(float f) { return (_Float16)f; }
// order-monotonic f32<->u32 mapping for atomicMax over signed floats
static __device__ __forceinline__ unsigned fenc(float f) {
    unsigned u = __float_as_uint(f);
    return (u & 0x80000000u) ? ~u : (u | 0x80000000u);
}
static __device__ __forceinline__ float fdec(unsigned u) {
    return __uint_as_float((u & 0x80000000u) ? (u ^ 0x80000000u) : ~u);
}
#define ENC_NEGINF 0x007FFFFFu   // fenc(-inf)

// async 16B global -> LDS (lane-contiguous dest), m97 pattern
static __device__ __forceinline__ void gl_lds16(const _Float16* g, _Float16* l) {
    __builtin_amdgcn_global_load_lds(
        (const __attribute__((address_space(1))) void*)g,
        (__attribute__((address_space(3))) void*)l, 16, 0, 0);
}

// flags[0]: 1 => masks u8, 0 => int32.  flags[1]: 1 => inputs f32, 0 => bf16.
__global__ void detect_kernel(const unsigned int* __restrict__ xm,
                              const unsigned int* __restrict__ xv,
                              int* __restrict__ flags)
{
    __shared__ int anyBig, cnt;
    if (threadIdx.x == 0) { anyBig = 0; cnt = 0; }
    __syncthreads();
    int big = 0;
    for (int i = threadIdx.x; i < 2048; i += 256)
        if (xm[i] > 1u) big = 1;
    if (big) atomicOr(&anyBig, 1);
    int c = 0;
    for (int i = threadIdx.x; i < 4096; i += 256) {
        const unsigned lo = xv[i] & 0xFFFFu;
        const unsigned e  = (lo >> 7) & 0xFFu;
        if ((lo & 0x7FFFu) == 0u || (e >= 96u && e <= 143u)) c++;
    }
    atomicAdd(&cnt, c);
    __syncthreads();
    if (threadIdx.x == 0) { flags[0] = anyBig; flags[1] = (cnt < 3600) ? 1 : 0; }
}

__global__ void init_kernel(unsigned* __restrict__ mr, float* __restrict__ lr,
                            unsigned* __restrict__ mc, float* __restrict__ lc, int n)
{
    const int i = blockIdx.x * 256 + threadIdx.x;
    if (i < n) { mr[i] = ENC_NEGINF; mc[i] = ENC_NEGINF; lr[i] = 0.f; lc[i] = 0.f; }
}

// [B][L][D] (bf16|f32) -> [B][D][L] f16, 64x64 tiles via LDS (pad 67)
__global__ __launch_bounds__(256)
void transpose_in_kernel(const void* __restrict__ in, _Float16* __restrict__ out,
                         const int* __restrict__ flags)
{
    const int b = blockIdx.z, lt = blockIdx.y, dt = blockIdx.x;
    const int inf32 = flags[1];
    __shared__ _Float16 T[64 * 67];
    const int t  = threadIdx.x;
    const int r0 = t >> 3;         // 0..31
    const int c0 = (t & 7) * 8;    // 0..56
    const unsigned short* in16 = (const unsigned short*)in + (long long)b * 2048 * 1024;
    const float*          inf  = (const float*)in + (long long)b * 2048 * 1024;
    #pragma unroll
    for (int it = 0; it < 2; it++) {
        const int ll = r0 + it * 32;
        const long long src = (long long)(lt * 64 + ll) * 1024 + dt * 64 + c0;
        _Float16 v[8];
        if (inf32) {
            const float* p = inf + src;
            #pragma unroll
            for (int k = 0; k < 8; k++) v[k] = f2h(p[k]);
        } else {
            short8 r = *(const short8*)(in16 + src);
            #pragma unroll
            for (int k = 0; k < 8; k++) v[k] = f2h(b2f((unsigned short)r[k]));
        }
        #pragma unroll
        for (int k = 0; k < 8; k++) T[(c0 + k) * 67 + ll] = v[k];
    }
    __syncthreads();
    #pragma unroll
    for (int it = 0; it < 2; it++) {
        const int dl = r0 + it * 32;
        half8 o;
        #pragma unroll
        for (int k = 0; k < 8; k++) o[k] = T[dl * 67 + c0 + k];
        *(half8*)&out[(long long)b * 1024 * 2048 +
                      (long long)(dt * 64 + dl) * 2048 + lt * 64 + c0] = o;
    }
}

// Per 64x64 s-tile: Pr=exp(s-mrow) f16 (row-major), Pct=exp(s-mcol)^T f16,
// atomicAdd lrow/lcol (shuffle-pre-reduced).
__global__ __launch_bounds__(256)
void transform_kernel(const float* __restrict__ s,
                      _Float16* __restrict__ Pr, _Float16* __restrict__ Pct,
                      const unsigned* __restrict__ mrow_u,
                      const unsigned* __restrict__ mcol_u,
                      float* __restrict__ lrow, float* __restrict__ lcol, int gb0)
{
    const int b  = blockIdx.z;          // chunk-local
    const int xt = blockIdx.y;          // x tile (rows of s)
    const int yt = blockIdx.x;          // y tile (cols of s)
    const long long sb  = (long long)b * 2048 * 2048;
    const int gbL = (gb0 + b) * 2048;
    __shared__ _Float16 T[64 * 67];
    const int t   = threadIdx.x;
    const int rl  = t >> 4;             // 0..15
    const int cl  = (t & 15) * 4;       // 0..60
    const int gy0 = yt * 64 + cl;
    float mc[4];
    #pragma unroll
    for (int j = 0; j < 4; j++) mc[j] = fdec(mcol_u[gbL + gy0 + j]);
    #pragma unroll
    for (int step = 0; step < 4; step++) {
        const int xl = rl + step * 16;
        const int gx = xt * 64 + xl;
        const float mr = fdec(mrow_u[gbL + gx]);
        const floatx4 v = *(const floatx4*)&s[sb + (long long)gx * 2048 + gy0];
        float er[4];
        #pragma unroll
        for (int j = 0; j < 4; j++) er[j] = __expf(v[j] - mr);
        half4 h;
        #pragma unroll
        for (int j = 0; j < 4; j++) h[j] = f2h(er[j]);
        *(half4*)&Pr[sb + (long long)gx * 2048 + gy0] = h;
        float rs = er[0] + er[1] + er[2] + er[3];
        rs += __shfl_xor(rs, 1); rs += __shfl_xor(rs, 2);
        rs += __shfl_xor(rs, 4); rs += __shfl_xor(rs, 8);
        if ((t & 15) == 0) atomicAdd(&lrow[gbL + gx], rs);
        #pragma unroll
        for (int j = 0; j < 4; j++)
            T[(cl + j) * 67 + xl] = f2h(__expf(v[j] - mc[j]));
    }
    __syncthreads();
    #pragma unroll
    for (int it = 0; it < 2; it++) {
        const int yl = (t >> 3) + it * 32;
        const int x0 = (t & 7) * 8;
        half8 o; float cs = 0.f;
        #pragma unroll
        for (int k = 0; k < 8; k++) { _Float16 e = T[yl * 67 + x0 + k]; o[k] = e; cs += (float)e; }
        *(half8*)&Pct[sb + (long long)(yt * 64 + yl) * 2048 + xt * 64 + x0] = o;
        cs += __shfl_xor(cs, 1); cs += __shfl_xor(cs, 2); cs += __shfl_xor(cs, 4);
        if ((t & 7) == 0) atomicAdd(&lcol[gbL + yt * 64 + yl], cs);
    }
}

// EPI: 0 = relu -> f16 ws (proj) | 1 = mask -> f32 s + atomicMax stats | 3 = v/l -> f32 out
// INRAW: operands are raw inputs (bf16|f32 via flags[1], manual convert-stage);
//        else f16 ws, staged via async global_load_lds width=16 (m97).
template<int EPI, bool INRAW>
__global__ __launch_bounds__(256, 2)
void gemm_kernel(const void* __restrict__ Agv, const void* __restrict__ Bgv,
                 void* __restrict__ Cgv,
                 unsigned* __restrict__ mrow_u, unsigned* __restrict__ mcol_u,
                 const float* __restrict__ lsum,
                 const int* __restrict__ xmask, const int* __restrict__ ymask,
                 const int* __restrict__ gflags, int gb0,
                 int K, int lda, int ldb, int ldc,
                 long long saA, long long saB, long long saC, int statL)
{
    const int b = blockIdx.z;
    const int inf32 = INRAW ? gflags[1] : 0;
    const unsigned short* Ag16 = (const unsigned short*)Agv + (long long)b * saA;
    const float*          Agf  = (const float*)Agv + (long long)b * saA;
    const unsigned short* Bg16 = (const unsigned short*)Bgv + (long long)b * saB;
    const float*          Bgf  = (const float*)Bgv + (long long)b * saB;
    const _Float16* Agh = (const _Float16*)Agv + (long long)b * saA;
    const _Float16* Bgh = (const _Float16*)Bgv + (long long)b * saB;

    __shared__ _Float16 As[BM * BK];
    __shared__ _Float16 Bs[BN * BK];

    const int t    = threadIdx.x;
    const int lane = t & 63;
    const int wave = t >> 6;
    const int wm   = (wave >> 1) << 6;
    const int wn   = (wave & 1) << 6;
    const int l16  = lane & 15;
    const int quad = lane >> 4;
    const int m0   = blockIdx.y * BM;
    const int n0   = blockIdx.x * BN;

    floatx4 acc[4][4];
    #pragma unroll
    for (int i = 0; i < 4; i++)
        #pragma unroll
        for (int j = 0; j < 4; j++)
            acc[i][j] = (floatx4){0.f, 0.f, 0.f, 0.f};

    for (int k0 = 0; k0 < K; k0 += BK) {
        if (!INRAW) {
            // async: each thread DMAs 16B; LDS dest = 16*t + 4096*it (contig/wave)
            #pragma unroll
            for (int it = 0; it < 4; it++) {
                const int e   = (t + it * 256) * 8;   // f16 elem index in tile
                const int row = e >> 6;
                const int kc  = e & 63;
                gl_lds16(Agh + (long long)(m0 + row) * lda + k0 + kc, &As[e]);
            }
            #pragma unroll
            for (int it = 0; it < 4; it++) {
                const int e   = (t + it * 256) * 8;
                const int row = e >> 6;
                const int kc  = e & 63;
                gl_lds16(Bgh + (long long)(n0 + row) * ldb + k0 + kc, &Bs[e]);
            }
        } else {
            #pragma unroll
            for (int c = t; c < BM * (BK / 8); c += 256) {
                const int row = c >> 3;
                const int kc  = (c & 7) << 3;
                half8 o;
                if (inf32) {
                    const float* src = Agf + (long long)(m0 + row) * lda + k0 + kc;
                    #pragma unroll
                    for (int j = 0; j < 8; j++) o[j] = f2h(src[j]);
                } else {
                    short8 r = *(const short8*)(Ag16 + (long long)(m0 + row) * lda + k0 + kc);
                    #pragma unroll
                    for (int j = 0; j < 8; j++) o[j] = f2h(b2f((unsigned short)r[j]));
                }
                *(half8*)&As[row * BK + kc] = o;   // lane-contiguous, 0 conflicts
            }
            #pragma unroll
            for (int c = t; c < BN * (BK / 8); c += 256) {
                const int row = c >> 3;
                const int kc  = (c & 7) << 3;
                half8 o;
                if (inf32) {
                    const float* src = Bgf + (long long)(n0 + row) * ldb + k0 + kc;
                    #pragma unroll
                    for (int j = 0; j < 8; j++) o[j] = f2h(src[j]);
                } else {
                    short8 r = *(const short8*)(Bg16 + (long long)(n0 + row) * ldb + k0 + kc);
                    #pragma unroll
                    for (int j = 0; j < 8; j++) o[j] = f2h(b2f((unsigned short)r[j]));
                }
                *(half8*)&Bs[row * BK + kc] = o;
            }
        }
        __syncthreads();   // drains vmcnt (incl. global_load_lds) + lgkm
        #pragma unroll
        for (int kk = 0; kk < BK; kk += 32) {
            half8 af[4], bfr[4];
            #pragma unroll
            for (int i = 0; i < 4; i++)
                af[i] = *(const half8*)&As[(wm + i * 16 + l16) * BK + kk + quad * 8];
            #pragma unroll
            for (int i = 0; i < 4; i++)
                bfr[i] = *(const half8*)&Bs[(wn + i * 16 + l16) * BK + kk + quad * 8];
            #pragma unroll
            for (int i = 0; i < 4; i++)
                #pragma unroll
                for (int j = 0; j < 4; j++)
                    acc[i][j] = __builtin_amdgcn_mfma_f32_16x16x32_f16(af[i], bfr[j], acc[i][j], 0, 0, 0);
        }
        __syncthreads();
    }

    int u8mode = 0;
    if (EPI == 1) u8mode = gflags[0];
    const unsigned char* xm8 = (const unsigned char*)xmask;
    const unsigned char* ym8 = (const unsigned char*)ymask;

    float rowmax[4][4], colmax[4];
    if (EPI == 1) {
        #pragma unroll
        for (int i = 0; i < 4; i++)
            #pragma unroll
            for (int r = 0; r < 4; r++) rowmax[i][r] = -1e38f;
        #pragma unroll
        for (int j = 0; j < 4; j++) colmax[j] = -1e38f;
    }

    // C/D layout: col=lane&15, row=quad*4+reg (m89-verified)
    #pragma unroll
    for (int i = 0; i < 4; i++) {
        #pragma unroll
        for (int j = 0; j < 4; j++) {
            #pragma unroll
            for (int r = 0; r < 4; r++) {
                const int grow = m0 + wm + i * 16 + quad * 4 + r;
                const int gcol = n0 + wn + j * 16 + l16;
                float v = acc[i][j][r];
                const long long cidx = (long long)b * saC + (long long)grow * ldc + gcol;
                if (EPI == 0) {
                    ((_Float16*)Cgv)[cidx] = f2h(fmaxf(v, 0.f));
                } else if (EPI == 1) {
                    const long long ix = (long long)(gb0 + b) * statL + grow;
                    const long long iy = (long long)(gb0 + b) * statL + gcol;
                    const bool mk = u8mode
                        ? ((xm8[ix] != 0) || (ym8[iy] != 0))
                        : ((xmask[ix] != 0) || (ymask[iy] != 0));
                    v = mk ? -1e30f : v;
                    ((float*)Cgv)[cidx] = v;
                    rowmax[i][r] = fmaxf(rowmax[i][r], v);
                    colmax[j]    = fmaxf(colmax[j], v);
                } else {
                    const float l = lsum[(long long)(gb0 + b) * statL + grow];
                    ((float*)Cgv)[cidx] = v / l;
                }
            }
        }
    }

    if (EPI == 1) {
        #pragma unroll
        for (int i = 0; i < 4; i++)
            #pragma unroll
            for (int r = 0; r < 4; r++) {
                float rm = rowmax[i][r];
                rm = fmaxf(rm, __shfl_xor(rm, 1)); rm = fmaxf(rm, __shfl_xor(rm, 2));
                rm = fmaxf(rm, __shfl_xor(rm, 4)); rm = fmaxf(rm, __shfl_xor(rm, 8));
                if (l16 == 0)
                    atomicMax(&mrow_u[(long long)(gb0 + b) * statL + m0 + wm + i * 16 + quad * 4 + r],
                              fenc(rm));
            }
        #pragma unroll
        for (int j = 0; j < 4; j++) {
            float cm = colmax[j];
            cm = fmaxf(cm, __shfl_xor(cm, 16)); cm = fmaxf(cm, __shfl_xor(cm, 32));
            if (quad == 0)
                atomicMax(&mcol_u[(long long)(gb0 + b) * statL + n0 + wn + j * 16 + l16],
                          fenc(cm));
        }
    }
}

extern "C" void kernel_launch(void* const* d_in, const int* in_sizes, int n_in,
                              void* d_out, int out_size, void* d_ws, size_t ws_size,
                              hipStream_t stream)
{
    const int B = 16, L = 2048, D = 1024, H = 1024;
    const void* x  = d_in[0];
    const void* y  = d_in[1];
    const int* xmask = (const int*)d_in[2];
    const int* ymask = (const int*)d_in[3];
    const void* Wx = d_in[4];
    const void* Wy = d_in[5];

    // ws: px | py | xT | yT | mrow_u | lrow | mcol_u | lcol | flags | s | Pr | Pct
    _Float16* px = (_Float16*)d_ws;
    _Float16* py = px + (size_t)B * L * H;
    _Float16* xT = py + (size_t)B * L * H;
    _Float16* yT = xT + (size_t)B * D * L;
    unsigned* mrow_u = (unsigned*)(yT + (size_t)B * D * L);
    float*    lrow   = (float*)(mrow_u + (size_t)B * L);
    unsigned* mcol_u = (unsigned*)(lrow + (size_t)B * L);
    float*    lcol   = (float*)(mcol_u + (size_t)B * L);
    int*      flags  = (int*)(lcol + (size_t)B * L);
    char*     dynbase = (char*)(flags + 16);

    const long long fixed_bytes = (long long)(dynbase - (char*)d_ws);
    const long long per_batch = (long long)L * L * 4 + 2LL * L * L * 2;  // s + Pr + Pct
    long long avail = (long long)ws_size - fixed_bytes;
    int nc = (int)(avail / per_batch);
    if (nc < 1) nc = 1;
    if (nc > B) nc = B;

    float* s  = (float*)dynbase;
    _Float16* Pr  = (_Float16*)(s + (size_t)nc * L * L);
    _Float16* Pct = Pr + (size_t)nc * L * L;

    float* yh = (float*)d_out;
    float* xh = yh + (size_t)B * L * D;

    dim3 blk(256);

    detect_kernel<<<1, 256, 0, stream>>>((const unsigned int*)xmask,
                                         (const unsigned int*)x, flags);
    init_kernel<<<dim3((B * L + 255) / 256), blk, 0, stream>>>(mrow_u, lrow, mcol_u, lcol, B * L);
    transpose_in_kernel<<<dim3(D / 64, L / 64, B), blk, 0, stream>>>(x, xT, flags);
    transpose_in_kernel<<<dim3(D / 64, L / 64, B), blk, 0, stream>>>(y, yT, flags);

    // projections (raw inputs, z=1 over flattened B*L)
    gemm_kernel<0, true><<<dim3(H / BN, (B * L) / BM, 1), blk, 0, stream>>>(
        x, Wx, px, nullptr, nullptr, nullptr, nullptr, nullptr, flags, 0,
        D, D, D, H, 0, 0, 0, 0);
    gemm_kernel<0, true><<<dim3(H / BN, (B * L) / BM, 1), blk, 0, stream>>>(
        y, Wy, py, nullptr, nullptr, nullptr, nullptr, nullptr, flags, 0,
        D, D, D, H, 0, 0, 0, 0);

    for (int b0 = 0; b0 < B; b0 += nc) {
        const int cur = (B - b0 < nc) ? (B - b0) : nc;
        // s = mask(px @ py^T) + row/col max atomics
        gemm_kernel<1, false><<<dim3(L / BN, L / BM, cur), blk, 0, stream>>>(
            px + (size_t)b0 * L * H, py + (size_t)b0 * L * H, s,
            mrow_u, mcol_u, nullptr, xmask, ymask, flags, b0,
            H, H, H, L, (long long)L * H, (long long)L * H, (long long)L * L, L);
        // Pr / Pct / lrow / lcol
        transform_kernel<<<dim3(L / 64, L / 64, cur), blk, 0, stream>>>(
            s, Pr, Pct, mrow_u, mcol_u, lrow, lcol, b0);
        // y_h = (Pr @ yT^T) / lrow
        gemm_kernel<3, false><<<dim3(D / BN, L / BM, cur), blk, 0, stream>>>(
            Pr, yT + (size_t)b0 * D * L, yh + (size_t)b0 * L * D,
            nullptr, nullptr, lrow, nullptr, nullptr, flags, b0,
            L, L, L, D, (long long)L * L, (long long)D * L, (long long)L * D, L);
        // x_h = (Pct @ xT^T) / lcol
        gemm_kernel<3, false><<<dim3(D / BN, L / BM, cur), blk, 0, stream>>>(
            Pct, xT + (size_t)b0 * D * L, xh + (size_t)b0 * L * D,
            nullptr, nullptr, lcol, nullptr, nullptr, flags, b0,
            L, L, L, D, (long long)L * L, (long long)D * L, (long long)L * D, L);
    }
    (void)in_sizes; (void)n_in; (void)out_size; (void)ws_size;
}